// Round 1
// baseline (780.893 us; speedup 1.0000x reference)
//
#include <hip/hip_runtime.h>

// SparseConv3d(32->64, k=3, s=2, p=1) on (21,800,704) grid, nnz=220939.
// Offset-major scatter: block = (k, point-chunk). Weight column for k lives
// in 32 VGPRs per lane (lane = cout). Features/coords via wave-uniform scalar
// loads. Validity per (point,k) reduces to parity + upper bound checks.

#define CIN  32
#define COUT 64
#define OXD  11
#define OYD  400
#define OZD  352

constexpr int PPW = 128;            // points per wave
constexpr int WPB = 4;              // waves per block (256 threads)
constexpr int PPB = PPW * WPB;      // 512 points per block

__global__ __launch_bounds__(256) void spconv_scatter(
    const float* __restrict__ feat,
    const int*   __restrict__ coords,
    const float* __restrict__ weight,
    float*       __restrict__ out,
    int nnz)
{
    const int lane = threadIdx.x & 63;
    const int wid  = threadIdx.x >> 6;
    const int k     = blockIdx.x % 27;   // adjacent blocks share point chunk
    const int chunk = blockIdx.x / 27;
    const int kx = k / 9, ky = (k / 3) % 3, kz = k % 3;

    // Preload this k's weight column: w[ci] = W[k][ci][lane]  (coalesced)
    float w[CIN];
    const float* __restrict__ Wk = weight + (size_t)k * CIN * COUT;
    #pragma unroll
    for (int ci = 0; ci < CIN; ++ci) w[ci] = Wk[ci * COUT + lane];

    const int base = chunk * PPB + wid * PPW;
    const int rem  = nnz - base;
    const int pend = rem < PPW ? rem : PPW;   // may be <=0 for tail waves

    for (int p = 0; p < pend; ++p) {
        // force wave-uniform (SGPR) point index -> scalar loads below
        const int n = __builtin_amdgcn_readfirstlane(base + p);
        const int cx = coords[3 * n + 0];
        const int cy = coords[3 * n + 1];
        const int cz = coords[3 * n + 2];
        // o = c + pad - k ; valid iff o>=0, o even, o/2 < OUT_DIM
        const int ox = cx + 1 - kx;
        const int oy = cy + 1 - ky;
        const int oz = cz + 1 - kz;
        // sign bit or parity bit set in any dim -> invalid
        const unsigned bad = (unsigned)(ox | oy | oz) & 0x80000001u;
        if (bad == 0u &&
            (ox >> 1) < OXD && (oy >> 1) < OYD && (oz >> 1) < OZD) {
            const float* __restrict__ fr = feat + (size_t)n * CIN;
            float a0 = 0.f, a1 = 0.f, a2 = 0.f, a3 = 0.f;
            #pragma unroll
            for (int ci = 0; ci < CIN; ci += 4) {
                a0 = fmaf(fr[ci + 0], w[ci + 0], a0);
                a1 = fmaf(fr[ci + 1], w[ci + 1], a1);
                a2 = fmaf(fr[ci + 2], w[ci + 2], a2);
                a3 = fmaf(fr[ci + 3], w[ci + 3], a3);
            }
            const float acc = (a0 + a1) + (a2 + a3);
            const size_t o =
                ((size_t)(ox >> 1) * OYD + (size_t)(oy >> 1)) * OZD + (size_t)(oz >> 1);
            atomicAdd(out + o * COUT + lane, acc);
        }
    }
}

extern "C" void kernel_launch(void* const* d_in, const int* in_sizes, int n_in,
                              void* d_out, int out_size, void* d_ws, size_t ws_size,
                              hipStream_t stream) {
    const float* feat   = (const float*)d_in[0];
    const int*   coords = (const int*)d_in[1];
    const float* weight = (const float*)d_in[2];
    float*       out    = (float*)d_out;

    const int nnz = in_sizes[0] / CIN;   // 220939

    // Output is densified: zero it (harness poisons with 0xAA every call).
    hipMemsetAsync(d_out, 0, (size_t)out_size * sizeof(float), stream);

    const int chunks = (nnz + PPB - 1) / PPB;
    dim3 grid(chunks * 27);
    spconv_scatter<<<grid, 256, 0, stream>>>(feat, coords, weight, out, nnz);
}